// Round 3
// baseline (231.384 us; speedup 1.0000x reference)
//
#include <hip/hip_runtime.h>
#include <hip/hip_bf16.h>

#define IN_F   1024
#define OUT_F  1024
#define NCH    9                  // 8 spline channels + 1 base(silu) channel
#define KDIM   (IN_F * NCH)       // 9216
#define BATCH  8192

// ---- GEMM geometry: 256x128 tile, BK=64, 8 waves (4M x 2N), triple-buffer ----
#define BM 256
#define BN 128
#define BK 64
#define NT (KDIM / BK)            // 144 K-tiles
#define ABUF_OFF (BM * BK)        // 16384 u16
#define BUFSZ (BM * BK + BN * BK) // 24576 u16 per buffer (48 KiB)

typedef __attribute__((ext_vector_type(4))) float  f32x4;
typedef __attribute__((ext_vector_type(8))) __bf16 bf16x8;

typedef __attribute__((address_space(3))) unsigned short       lds_u16;
typedef const __attribute__((address_space(1))) unsigned short glb_u16;

__device__ inline unsigned short f2bf(float f) {
    union { float f; unsigned int u; } v; v.f = f;
    unsigned int u = v.u;
    unsigned int r = (u + 0x7FFFu + ((u >> 16) & 1u)) >> 16;   // RNE
    return (unsigned short)r;
}

// ---------------------------------------------------------------------------
// Kernel 1: combined weights  Wc[o][f*9 + c] (bf16)
// thread = (o, f-block of 8): reads 64 f32 spline w + 8 scaler + 8 base,
// writes 72 u16 = 9 x dwordx4 (16B-aligned: 72 u16 = 144 B).
// ---------------------------------------------------------------------------
__global__ void wgt_kernel(const float* __restrict__ bw,
                           const float* __restrict__ sw,
                           const float* __restrict__ sc,
                           unsigned short* __restrict__ W) {
    int idx = blockIdx.x * blockDim.x + threadIdx.x;     // o*128 + fb
    if (idx >= OUT_F * (IN_F / 8)) return;
    const float4* swp = (const float4*)(sw + (size_t)idx * 64);
    const float4* scp = (const float4*)(sc + (size_t)idx * 8);
    const float4* bwp = (const float4*)(bw + (size_t)idx * 8);
    float4 sc0 = scp[0], sc1 = scp[1];
    float4 bw0 = bwp[0], bw1 = bwp[1];
    float scl[8] = {sc0.x, sc0.y, sc0.z, sc0.w, sc1.x, sc1.y, sc1.z, sc1.w};
    float bas[8] = {bw0.x, bw0.y, bw0.z, bw0.w, bw1.x, bw1.y, bw1.z, bw1.w};

    unsigned short tmp[72];
#pragma unroll
    for (int e = 0; e < 8; ++e) {
        float4 w0 = swp[e * 2], w1 = swp[e * 2 + 1];
        float s = scl[e];
        tmp[e * 9 + 0] = f2bf(w0.x * s);
        tmp[e * 9 + 1] = f2bf(w0.y * s);
        tmp[e * 9 + 2] = f2bf(w0.z * s);
        tmp[e * 9 + 3] = f2bf(w0.w * s);
        tmp[e * 9 + 4] = f2bf(w1.x * s);
        tmp[e * 9 + 5] = f2bf(w1.y * s);
        tmp[e * 9 + 6] = f2bf(w1.z * s);
        tmp[e * 9 + 7] = f2bf(w1.w * s);
        tmp[e * 9 + 8] = f2bf(bas[e]);
    }
    unsigned int u[36];
#pragma unroll
    for (int k = 0; k < 36; ++k)
        u[k] = (unsigned int)tmp[2 * k] | ((unsigned int)tmp[2 * k + 1] << 16);
    uint4* dst = (uint4*)(W + (size_t)idx * 72);
#pragma unroll
    for (int i = 0; i < 9; ++i) {
        uint4 v; v.x = u[i * 4]; v.y = u[i * 4 + 1]; v.z = u[i * 4 + 2]; v.w = u[i * 4 + 3];
        dst[i] = v;
    }
}

// ---------------------------------------------------------------------------
// Kernel 2: activations  A[r][f*9 + c] (bf16), 8 features per thread,
// 9 x dwordx4 stores. Knots g_i = -2.2 + 0.4*i; closed-form cubic pieces.
// ---------------------------------------------------------------------------
__global__ void act_kernel(const float* __restrict__ x,
                           unsigned short* __restrict__ A) {
    int idx = blockIdx.x * blockDim.x + threadIdx.x;     // r*128 + fb
    if (idx >= BATCH * (IN_F / 8)) return;
    const float4* xp = (const float4*)(x + (size_t)idx * 8);
    float4 x0 = xp[0], x1 = xp[1];
    float xs[8] = {x0.x, x0.y, x0.z, x0.w, x1.x, x1.y, x1.z, x1.w};

    unsigned short tmp[72];
#pragma unroll
    for (int e = 0; e < 8; ++e) {
        float xv = xs[e];
        float s  = xv / (1.0f + __expf(-xv));            // silu

        float t  = (xv + 2.2f) * 2.5f;                   // (x - g0)/h
        float jf = floorf(t);
        int   j  = (int)jf;
        float u  = t - jf;
        float u2 = u * u, u3 = u2 * u;
        float p0 = u3 * (1.0f / 6.0f);
        float p1 = (-3.0f * u3 + 3.0f * u2 + 3.0f * u + 1.0f) * (1.0f / 6.0f);
        float p2 = (3.0f * u3 - 6.0f * u2 + 4.0f) * (1.0f / 6.0f);
        float om = 1.0f - u;
        float p3 = om * om * om * (1.0f / 6.0f);
        bool valid = (xv >= -2.2f) && (xv < 2.2f);

#pragma unroll
        for (int c = 0; c < 8; ++c) {
            int p = j - c;
            float v = 0.0f;
            if (valid)
                v = (p == 0) ? p0 : (p == 1) ? p1 : (p == 2) ? p2 : (p == 3) ? p3 : 0.0f;
            tmp[e * 9 + c] = f2bf(v);
        }
        tmp[e * 9 + 8] = f2bf(s);
    }
    unsigned int u[36];
#pragma unroll
    for (int k = 0; k < 36; ++k)
        u[k] = (unsigned int)tmp[2 * k] | ((unsigned int)tmp[2 * k + 1] << 16);
    uint4* dst = (uint4*)(A + (size_t)idx * 72);
#pragma unroll
    for (int i = 0; i < 9; ++i) {
        uint4 v; v.x = u[i * 4]; v.y = u[i * 4 + 1]; v.z = u[i * 4 + 2]; v.w = u[i * 4 + 3];
        dst[i] = v;
    }
}

// ---------------------------------------------------------------------------
// Kernel 3: GEMM  C[M][1024] = A[M][9216] x Wc[1024][9216]^T  (bf16->f32)
// Triple-buffered LDS (3x48KB), prefetch distance 2 K-tiles, counted
// vmcnt(6) at tile boundary (never 0 in steady state), 4 phases/tile with
// per-phase {ds_read || stage -> barrier -> setprio MFMA -> barrier},
// T2 LDS XOR swizzle via pre-swizzled global source, XCD-chunked swizzle.
// ---------------------------------------------------------------------------

#define DECLA(i) \
    const int ciA##i = (i) * 512 + tid; \
    const unsigned short* srcA##i = A + (size_t)(m0 + (ciA##i >> 3)) * KDIM \
        + ((((ciA##i) & 7) ^ ((ciA##i >> 3) & 7)) << 3); \
    const int ldsA##i = (ciA##i) << 3;

#define DECLB(i) \
    const int ciB##i = (i) * 512 + tid; \
    const unsigned short* srcB##i = W + (size_t)(n0 + (ciB##i >> 3)) * KDIM \
        + ((((ciB##i) & 7) ^ ((ciB##i >> 3) & 7)) << 3); \
    const int ldsB##i = ABUF_OFF + ((ciB##i) << 3);

#define STAGE_A(i) do { \
    __builtin_amdgcn_global_load_lds((glb_u16*)srcA##i, (lds_u16*)nb + ldsA##i, 16, 0, 0); \
    srcA##i += BK; } while (0)

#define STAGE_B(i) do { \
    __builtin_amdgcn_global_load_lds((glb_u16*)srcB##i, (lds_u16*)nb + ldsB##i, 16, 0, 0); \
    srcB##i += BK; } while (0)

// swizzled fragment read: lds col16 = global col16 ^ (row&7); row&7 == lane&7
#define RDA(mi, kk) (*(const bf16x8*)&bufA[(rowa + (mi) * 16) * BK + ((((kk) * 4 + lhi) ^ l7) << 3)])
#define RDB(ni, kk) (*(const bf16x8*)&bufB[(rowb + (ni) * 16) * BK + ((((kk) * 4 + lhi) ^ l7) << 3)])

#define MM(mi, ni) do { \
    acc[mi][ni] = __builtin_amdgcn_mfma_f32_16x16x32_bf16(a##mi##0, b##ni##0, acc[mi][ni], 0, 0, 0); \
    acc[mi][ni] = __builtin_amdgcn_mfma_f32_16x16x32_bf16(a##mi##1, b##ni##1, acc[mi][ni], 0, 0, 0); \
} while (0)

__global__ __launch_bounds__(512, 2) void gemm_3b(
    const unsigned short* __restrict__ A,
    const unsigned short* __restrict__ W,
    float* __restrict__ C, int mblocks) {
    __shared__ unsigned short lds[3 * BUFSZ];            // 144 KiB

    const int tid  = threadIdx.x;
    const int wave = tid >> 6;
    const int lane = tid & 63;
    const int lm16 = lane & 15;
    const int lhi  = lane >> 4;
    const int l7   = lane & 7;

    // XCD-chunked bijective swizzle: nwg = mblocks*8 (divisible by 8)
    const int l  = (blockIdx.x & 7) * mblocks + (blockIdx.x >> 3);
    const int lm = l >> 3;                               // shares A-panel across ln
    const int ln = l & 7;
    const int m0 = lm * BM;
    const int n0 = ln * BN;

    const int wr = wave >> 1;                            // 0..3 (M)
    const int wc = wave & 1;                             // 0..1 (N)
    const int rowa = wr * 64 + lm16;
    const int rowb = wc * 64 + lm16;

    f32x4 acc[4][4];
#pragma unroll
    for (int i = 0; i < 4; ++i)
#pragma unroll
        for (int jn = 0; jn < 4; ++jn) acc[i][jn] = (f32x4)(0.0f);

    DECLA(0) DECLA(1) DECLA(2) DECLA(3)
    DECLB(0) DECLB(1)

    // prologue: stage K-tile 0 -> buf0, K-tile 1 -> buf1; wait only tile 0
    {
        unsigned short* nb = lds;
        STAGE_A(0); STAGE_A(1); STAGE_A(2); STAGE_A(3); STAGE_B(0); STAGE_B(1);
    }
    {
        unsigned short* nb = lds + BUFSZ;
        STAGE_A(0); STAGE_A(1); STAGE_A(2); STAGE_A(3); STAGE_B(0); STAGE_B(1);
    }
    asm volatile("s_waitcnt vmcnt(6)" ::: "memory");
    __builtin_amdgcn_s_barrier();

    int cb = 0;                                          // t % 3
    for (int t = 0; t < NT; ++t) {
        const unsigned short* bufA = lds + cb * BUFSZ;
        const unsigned short* bufB = bufA + ABUF_OFF;
        unsigned short* nb = lds + (cb == 0 ? 2 * BUFSZ : (size_t)(cb - 1) * BUFSZ); // (t+2)%3
        const bool pf = (t + 2 < NT);

        bf16x8 a00, a01, a10, a11, a20, a21, a30, a31;
        bf16x8 b00, b01, b10, b11, b20, b21, b30, b31;

        // ---- phase 0: quadrant (mi 0-1, ni 0-1) ----
        a00 = RDA(0, 0); a01 = RDA(0, 1); a10 = RDA(1, 0); a11 = RDA(1, 1);
        b00 = RDB(0, 0); b01 = RDB(0, 1); b10 = RDB(1, 0); b11 = RDB(1, 1);
        if (pf) { STAGE_A(0); STAGE_A(1); }
        __builtin_amdgcn_s_barrier();
        __builtin_amdgcn_s_setprio(1);
        MM(0, 0); MM(0, 1); MM(1, 0); MM(1, 1);
        __builtin_amdgcn_s_setprio(0);
        __builtin_amdgcn_s_barrier();

        // ---- phase 1: quadrant (mi 0-1, ni 2-3) ----
        b20 = RDB(2, 0); b21 = RDB(2, 1); b30 = RDB(3, 0); b31 = RDB(3, 1);
        if (pf) { STAGE_A(2); STAGE_A(3); }
        __builtin_amdgcn_s_barrier();
        __builtin_amdgcn_s_setprio(1);
        MM(0, 2); MM(0, 3); MM(1, 2); MM(1, 3);
        __builtin_amdgcn_s_setprio(0);
        __builtin_amdgcn_s_barrier();

        // ---- phase 2: quadrant (mi 2-3, ni 2-3) ----
        a20 = RDA(2, 0); a21 = RDA(2, 1); a30 = RDA(3, 0); a31 = RDA(3, 1);
        if (pf) { STAGE_B(0); STAGE_B(1); }
        __builtin_amdgcn_s_barrier();
        __builtin_amdgcn_s_setprio(1);
        MM(2, 2); MM(2, 3); MM(3, 2); MM(3, 3);
        __builtin_amdgcn_s_setprio(0);
        __builtin_amdgcn_s_barrier();

        // ---- phase 3: quadrant (mi 2-3, ni 0-1); counted tile-boundary wait ----
        __builtin_amdgcn_s_setprio(1);
        MM(2, 0); MM(2, 1); MM(3, 0); MM(3, 1);
        __builtin_amdgcn_s_setprio(0);
        if (pf) asm volatile("s_waitcnt vmcnt(6)" ::: "memory");   // t+1 landed, t+2 in flight
        else    asm volatile("s_waitcnt vmcnt(0)" ::: "memory");   // epilogue drain
        __builtin_amdgcn_s_barrier();

        cb = (cb == 2) ? 0 : cb + 1;
    }

    // epilogue: C/D layout col = lane&15, row = (lane>>4)*4 + r
    const int col0 = n0 + wc * 64 + lm16;
    const int row0 = m0 + wr * 64 + (lhi << 2);
#pragma unroll
    for (int mi = 0; mi < 4; ++mi)
#pragma unroll
        for (int ni = 0; ni < 4; ++ni)
#pragma unroll
            for (int r = 0; r < 4; ++r)
                C[(size_t)(row0 + mi * 16 + r) * OUT_F + (col0 + ni * 16)] = acc[mi][ni][r];
}

// ---------------------------------------------------------------------------
extern "C" void kernel_launch(void* const* d_in, const int* in_sizes, int n_in,
                              void* d_out, int out_size, void* d_ws, size_t ws_size,
                              hipStream_t stream) {
    const float* x             = (const float*)d_in[0];
    const float* base_weight   = (const float*)d_in[1];
    const float* spline_weight = (const float*)d_in[2];
    const float* spline_scaler = (const float*)d_in[3];
    // d_in[4] = grid (uniform, constants hardcoded)
    float* out = (float*)d_out;

    unsigned short* Wc = (unsigned short*)d_ws;
    const size_t wbytes = (size_t)OUT_F * KDIM * sizeof(unsigned short);   // ~18.9 MB
    unsigned short* Abuf = (unsigned short*)((char*)d_ws + wbytes);

    wgt_kernel<<<(OUT_F * (IN_F / 8) + 255) / 256, 256, 0, stream>>>(
        base_weight, spline_weight, spline_scaler, Wc);

    act_kernel<<<(BATCH * (IN_F / 8) + 255) / 256, 256, 0, stream>>>(x, Abuf);

    int mblocks = BATCH / BM;                            // 32
    gemm_3b<<<mblocks * 8, 512, 0, stream>>>(Abuf, Wc, out, mblocks);
}

// Round 4
// 208.245 us; speedup vs baseline: 1.1111x; 1.1111x over previous
//
#include <hip/hip_runtime.h>
#include <hip/hip_bf16.h>

#define IN_F   1024
#define OUT_F  1024
#define NCH    9
#define KDIM   9216               // 9 channels * 1024 features, channel-major: k = c*1024 + f
#define BATCH  8192

// ---- GEMM geometry: 256x256 tile, BK=64, 8 waves (2M x 4N), K-split x2 ----
#define BM 256
#define BN 256
#define BK 64
#define KHALF 4608
#define NTK (KHALF / BK)          // 72 K-tiles per half
#define TSZ 16384                 // u16 per A or B tile buffer (32 KiB)

typedef __attribute__((ext_vector_type(4))) float  f32x4;
typedef __attribute__((ext_vector_type(8))) __bf16 bf16x8;

typedef __attribute__((address_space(3))) unsigned short       lds_u16;
typedef const __attribute__((address_space(1))) unsigned short glb_u16;

__device__ inline unsigned short f2bf(float f) {
    union { float f; unsigned int u; } v; v.f = f;
    unsigned int u = v.u;
    unsigned int r = (u + 0x7FFFu + ((u >> 16) & 1u)) >> 16;   // RNE
    return (unsigned short)r;
}

// ---------------------------------------------------------------------------
// Kernel 1: combined weights, channel-major: W[o][c*1024 + f]
//   c=0..7: spline_weight[o][f][c]*scaler[o][f];  c=8: base_weight[o][f]
// Stores are lane-contiguous (consecutive f) -> fully coalesced.
// ---------------------------------------------------------------------------
__global__ void wgt_kernel(const float* __restrict__ bw,
                           const float* __restrict__ sw,
                           const float* __restrict__ sc,
                           unsigned short* __restrict__ W) {
    int idx = blockIdx.x * blockDim.x + threadIdx.x;     // o*1024 + f
    if (idx >= OUT_F * IN_F) return;
    int o = idx >> 10, f = idx & 1023;
    float scale = sc[idx];
    const float4* swp = (const float4*)(sw + (size_t)idx * 8);
    float4 w0 = swp[0], w1 = swp[1];
    unsigned short* Wb = W + (size_t)o * KDIM + f;
    Wb[0 * 1024] = f2bf(w0.x * scale);
    Wb[1 * 1024] = f2bf(w0.y * scale);
    Wb[2 * 1024] = f2bf(w0.z * scale);
    Wb[3 * 1024] = f2bf(w0.w * scale);
    Wb[4 * 1024] = f2bf(w1.x * scale);
    Wb[5 * 1024] = f2bf(w1.y * scale);
    Wb[6 * 1024] = f2bf(w1.z * scale);
    Wb[7 * 1024] = f2bf(w1.w * scale);
    Wb[8 * 1024] = f2bf(bw[idx]);
}

// ---------------------------------------------------------------------------
// Kernel 2: activations, channel-major: A[r][c*1024 + f]
// 4 features/thread: float4 load, 9 x 8B coalesced stores.
// ---------------------------------------------------------------------------
__global__ void act_kernel(const float* __restrict__ x,
                           unsigned short* __restrict__ A) {
    int idx = blockIdx.x * blockDim.x + threadIdx.x;     // r*256 + f4
    if (idx >= BATCH * 256) return;
    float4 xv = ((const float4*)x)[idx];
    float xs[4] = {xv.x, xv.y, xv.z, xv.w};

    unsigned short vals[4][9];
#pragma unroll
    for (int e = 0; e < 4; ++e) {
        float v  = xs[e];
        float s  = v / (1.0f + __expf(-v));              // silu

        float t  = (v + 2.2f) * 2.5f;                    // (x - g0)/h
        float jf = floorf(t);
        int   j  = (int)jf;
        float u  = t - jf;
        float u2 = u * u, u3 = u2 * u;
        float p0 = u3 * (1.0f / 6.0f);
        float p1 = (-3.0f * u3 + 3.0f * u2 + 3.0f * u + 1.0f) * (1.0f / 6.0f);
        float p2 = (3.0f * u3 - 6.0f * u2 + 4.0f) * (1.0f / 6.0f);
        float om = 1.0f - u;
        float p3 = om * om * om * (1.0f / 6.0f);
        bool valid = (v >= -2.2f) && (v < 2.2f);

#pragma unroll
        for (int c = 0; c < 8; ++c) {
            int p = j - c;
            float bv = 0.0f;
            if (valid)
                bv = (p == 0) ? p0 : (p == 1) ? p1 : (p == 2) ? p2 : (p == 3) ? p3 : 0.0f;
            vals[e][c] = f2bf(bv);
        }
        vals[e][8] = f2bf(s);
    }

    int r = idx >> 8, f4 = idx & 255;
    unsigned short* base = A + (size_t)r * KDIM + f4 * 4;
#pragma unroll
    for (int c = 0; c < 9; ++c) {
        uint2 pk;
        pk.x = (unsigned int)vals[0][c] | ((unsigned int)vals[1][c] << 16);
        pk.y = (unsigned int)vals[2][c] | ((unsigned int)vals[3][c] << 16);
        *(uint2*)(base + (size_t)c * 1024) = pk;
    }
}

// ---------------------------------------------------------------------------
// Kernel 3: K-split GEMM.  256 blocks: kb=0 -> C, kb=1 -> P (or atomicAdd).
// Wave tile 128x64 (43.7 FLOP/B from LDS -> MFMA-bound). dbuf 128 KiB.
// All 8 stage loads issued at tile start; vmcnt(0) at tile end waits on
// ~2000-cycle-old loads. T2 swizzle (0 conflicts, validated r2/r3).
// ---------------------------------------------------------------------------
#define DECLS(q) \
    const int ci##q = (q) * 512 + tid; \
    const int rr##q = ci##q >> 3; \
    const int sw##q = (((ci##q & 7) ^ (rr##q & 7)) << 3); \
    const unsigned short* srcA##q = Ap + (size_t)(m0 + rr##q) * KDIM + kbase + sw##q; \
    const unsigned short* srcB##q = Wp + (size_t)(n0 + rr##q) * KDIM + kbase + sw##q; \
    const int lo##q = ci##q << 3;

#define STAGE(q, pb) do { \
    __builtin_amdgcn_global_load_lds((glb_u16*)srcA##q, (lds_u16*)(lds + (pb) * TSZ) + lo##q, 16, 0, 0); \
    srcA##q += BK; \
    __builtin_amdgcn_global_load_lds((glb_u16*)srcB##q, (lds_u16*)(lds + 2 * TSZ + (pb) * TSZ) + lo##q, 16, 0, 0); \
    srcB##q += BK; \
} while (0)

#define RDA(buf, mi, kk) (*(const bf16x8*)&(buf)[(rowa + (mi) * 16) * BK + ((((kk) * 4 + lhi) ^ l7) << 3)])
#define RDB(buf, ni, kk) (*(const bf16x8*)&(buf)[(rowb + (ni) * 16) * BK + ((((kk) * 4 + lhi) ^ l7) << 3)])

#define MM1(ai, mi, ni) \
    acc[mi][ni] = __builtin_amdgcn_mfma_f32_16x16x32_bf16(a[ai][0], b[ni][0], acc[mi][ni], 0, 0, 0); \
    acc[mi][ni] = __builtin_amdgcn_mfma_f32_16x16x32_bf16(a[ai][1], b[ni][1], acc[mi][ni], 0, 0, 0);

#define MMQ(mh, nh) \
    MM1(0, (mh) * 4 + 0, (nh) * 2 + 0) MM1(0, (mh) * 4 + 0, (nh) * 2 + 1) \
    MM1(1, (mh) * 4 + 1, (nh) * 2 + 0) MM1(1, (mh) * 4 + 1, (nh) * 2 + 1) \
    MM1(2, (mh) * 4 + 2, (nh) * 2 + 0) MM1(2, (mh) * 4 + 2, (nh) * 2 + 1) \
    MM1(3, (mh) * 4 + 3, (nh) * 2 + 0) MM1(3, (mh) * 4 + 3, (nh) * 2 + 1)

#define TILE(pb, t) do { \
    const unsigned short* bufA = lds + (pb) * TSZ; \
    const unsigned short* bufB = lds + 2 * TSZ + (pb) * TSZ; \
    if ((t) + 1 < NTK) { STAGE(0, (pb) ^ 1); STAGE(1, (pb) ^ 1); STAGE(2, (pb) ^ 1); STAGE(3, (pb) ^ 1); } \
    /* ph0: A mh0 + B nh0 reads, MFMA (mi0-3)x(ni0-1) */ \
    a[0][0] = RDA(bufA, 0, 0); a[0][1] = RDA(bufA, 0, 1); a[1][0] = RDA(bufA, 1, 0); a[1][1] = RDA(bufA, 1, 1); \
    a[2][0] = RDA(bufA, 2, 0); a[2][1] = RDA(bufA, 2, 1); a[3][0] = RDA(bufA, 3, 0); a[3][1] = RDA(bufA, 3, 1); \
    b[0][0] = RDB(bufB, 0, 0); b[0][1] = RDB(bufB, 0, 1); b[1][0] = RDB(bufB, 1, 0); b[1][1] = RDB(bufB, 1, 1); \
    __builtin_amdgcn_s_barrier(); \
    __builtin_amdgcn_s_setprio(1); MMQ(0, 0) __builtin_amdgcn_s_setprio(0); \
    __builtin_amdgcn_s_barrier(); \
    /* ph1: B nh1 reads, MFMA (mi0-3)x(ni2-3) */ \
    b[2][0] = RDB(bufB, 2, 0); b[2][1] = RDB(bufB, 2, 1); b[3][0] = RDB(bufB, 3, 0); b[3][1] = RDB(bufB, 3, 1); \
    __builtin_amdgcn_s_barrier(); \
    __builtin_amdgcn_s_setprio(1); MMQ(0, 1) __builtin_amdgcn_s_setprio(0); \
    __builtin_amdgcn_s_barrier(); \
    /* ph2: A mh1 reads, MFMA (mi4-7)x(ni2-3) */ \
    a[0][0] = RDA(bufA, 4, 0); a[0][1] = RDA(bufA, 4, 1); a[1][0] = RDA(bufA, 5, 0); a[1][1] = RDA(bufA, 5, 1); \
    a[2][0] = RDA(bufA, 6, 0); a[2][1] = RDA(bufA, 6, 1); a[3][0] = RDA(bufA, 7, 0); a[3][1] = RDA(bufA, 7, 1); \
    __builtin_amdgcn_s_barrier(); \
    __builtin_amdgcn_s_setprio(1); MMQ(1, 1) __builtin_amdgcn_s_setprio(0); \
    __builtin_amdgcn_s_barrier(); \
    /* ph3: MFMA (mi4-7)x(ni0-1), tile-boundary wait (loads ~2000cy old) */ \
    __builtin_amdgcn_s_setprio(1); MMQ(1, 0) __builtin_amdgcn_s_setprio(0); \
    asm volatile("s_waitcnt vmcnt(0)" ::: "memory"); \
    __builtin_amdgcn_s_barrier(); \
} while (0)

__global__ __launch_bounds__(512, 2) void gemm_ks(
    const unsigned short* __restrict__ Ap,
    const unsigned short* __restrict__ Wp,
    float* __restrict__ C, float* __restrict__ P, int mode) {
    __shared__ unsigned short lds[4 * TSZ];              // A0 A1 B0 B1 = 128 KiB

    const int tid  = threadIdx.x;
    const int wave = tid >> 6;
    const int lane = tid & 63;
    const int lm16 = lane & 15;
    const int lhi  = lane >> 4;
    const int l7   = lane & 7;

    // bid -> (kb, m, n): XCD x = bid&7 holds fixed (kb = x>>2, mgroup = x&3);
    // within an XCD: 8 m-panels x 4 n -> A,B panels L2-resident per XCD.
    const int bid  = blockIdx.x;
    const int mg   = bid & 3;
    const int kb   = (bid >> 2) & 1;
    const int j    = bid >> 3;
    const int m0   = (mg * 8 + (j >> 2)) * BM;
    const int n0   = (j & 3) * BN;
    const int kbase = kb * KHALF;

    const int wr = wave >> 2;                            // 0..1 (M)
    const int wc = wave & 3;                             // 0..3 (N)
    const int rowa = wr * 128 + lm16;
    const int rowb = wc * 64 + lm16;

    f32x4 acc[8][4];
#pragma unroll
    for (int i = 0; i < 8; ++i)
#pragma unroll
        for (int jn = 0; jn < 4; ++jn) acc[i][jn] = (f32x4)(0.0f);

    DECLS(0) DECLS(1) DECLS(2) DECLS(3)

    // prologue: stage K-tile 0 into parity 0
    STAGE(0, 0); STAGE(1, 0); STAGE(2, 0); STAGE(3, 0);
    asm volatile("s_waitcnt vmcnt(0)" ::: "memory");
    __builtin_amdgcn_s_barrier();

    bf16x8 a[4][2], b[4][2];
    for (int tt = 0; tt < NTK; tt += 2) {
        TILE(0, tt);
        TILE(1, tt + 1);
    }

    // epilogue: C/D layout col = lane&15, row = (lane>>4)*4 + r
    const int row0 = m0 + wr * 128 + (lhi << 2);
    const int col0 = n0 + wc * 64 + lm16;
    if (mode) {
#pragma unroll
        for (int mi = 0; mi < 8; ++mi)
#pragma unroll
            for (int ni = 0; ni < 4; ++ni)
#pragma unroll
                for (int r = 0; r < 4; ++r)
                    atomicAdd(&C[(size_t)(row0 + mi * 16 + r) * OUT_F + (col0 + ni * 16)], acc[mi][ni][r]);
    } else {
        float* dst = kb ? P : C;
#pragma unroll
        for (int mi = 0; mi < 8; ++mi)
#pragma unroll
            for (int ni = 0; ni < 4; ++ni)
#pragma unroll
                for (int r = 0; r < 4; ++r)
                    dst[(size_t)(row0 + mi * 16 + r) * OUT_F + (col0 + ni * 16)] = acc[mi][ni][r];
    }
}

// ---------------------------------------------------------------------------
// Kernel 4: C += P (K-split reduction), float4.
// ---------------------------------------------------------------------------
__global__ void add_kernel(float* __restrict__ C, const float* __restrict__ P) {
    int i = blockIdx.x * blockDim.x + threadIdx.x;
    if (i >= BATCH * OUT_F / 4) return;
    f32x4* c4 = (f32x4*)C;
    const f32x4* p4 = (const f32x4*)P;
    c4[i] = c4[i] + p4[i];
}

// ---------------------------------------------------------------------------
extern "C" void kernel_launch(void* const* d_in, const int* in_sizes, int n_in,
                              void* d_out, int out_size, void* d_ws, size_t ws_size,
                              hipStream_t stream) {
    const float* x             = (const float*)d_in[0];
    const float* base_weight   = (const float*)d_in[1];
    const float* spline_weight = (const float*)d_in[2];
    const float* spline_scaler = (const float*)d_in[3];
    float* out = (float*)d_out;

    const size_t wbytes = (size_t)OUT_F * KDIM * 2;      // 18.9 MB
    const size_t abytes = (size_t)BATCH * KDIM * 2;      // 151 MB
    const size_t pbytes = (size_t)BATCH * OUT_F * 4;     // 33.5 MB
    unsigned short* Wc   = (unsigned short*)d_ws;
    unsigned short* Abuf = (unsigned short*)((char*)d_ws + wbytes);
    float*          P    = (float*)((char*)d_ws + wbytes + abytes);

    const int mode = (ws_size >= wbytes + abytes + pbytes) ? 0 : 1;
    if (mode == 1)
        hipMemsetAsync(d_out, 0, pbytes, stream);        // atomic fallback needs zeroed C

    wgt_kernel<<<(OUT_F * IN_F) / 256, 256, 0, stream>>>(
        base_weight, spline_weight, spline_scaler, Wc);
    act_kernel<<<(BATCH * 256) / 256, 256, 0, stream>>>(x, Abuf);

    gemm_ks<<<256, 512, 0, stream>>>(Abuf, Wc, out, P, mode);

    if (mode == 0)
        add_kernel<<<(BATCH * OUT_F / 4 + 255) / 256, 256, 0, stream>>>(out, P);
}